// Round 6
// baseline (106.546 us; speedup 1.0000x reference)
//
#include <hip/hip_runtime.h>

typedef short v8s __attribute__((ext_vector_type(8)));
typedef short v4s __attribute__((ext_vector_type(4)));
typedef float v4f __attribute__((ext_vector_type(4)));

#define LOG2E 1.44269504088896340736f

// ---- d_ws layout (bytes) ----
#define WS_FBF_T 0u          // u16 [8][4096][64]  f transposed (n-major)
#define WS_FBF   4194304u    // u16 [8][64][4096]  f natural (c-major rows)
#define WS_G     8388608u    // f32 [8][4096]      row squared-norms
#define WS_BMAX  8519680u    // f32 [8][32]        per-block partial max of g
#define WS_NEED  8521728u

__device__ __forceinline__ unsigned short f2bf_rne(float f) {
  unsigned int u = __builtin_bit_cast(unsigned int, f);
  u += 0x7FFFu + ((u >> 16) & 1u);
  return (unsigned short)(u >> 16);
}

// pack hi16(hi):hi16(lo) in one v_perm_b32 (RTZ bf16 pair)
__device__ __forceinline__ unsigned int pack_hi16(float hi, float lo) {
#if defined(__has_builtin) && __has_builtin(__builtin_amdgcn_perm)
  return __builtin_amdgcn_perm(__builtin_bit_cast(unsigned int, hi),
                               __builtin_bit_cast(unsigned int, lo), 0x07060302u);
#else
  return (__builtin_bit_cast(unsigned int, hi) & 0xFFFF0000u) |
         (__builtin_bit_cast(unsigned int, lo) >> 16);
#endif
}

// ============ pre-pass (transpose-free, no LDS in hot path) ============
// 256 blocks (b x 32 n-chunks of 128) x 256 threads. Thread owns one n and
// half the channels: all x loads / fbf stores are lane-consecutive in n
// (coalesced); fbf_t row stores are b128.
__global__ __launch_bounds__(256) void prep_kernel(
    const float* __restrict__ x, unsigned short* __restrict__ fbf_t,
    unsigned short* __restrict__ fbf, float* __restrict__ g, float* __restrict__ bmax) {
  __shared__ float red[128];
  __shared__ float wmax[2];
  const int t = threadIdx.x;
  const int b = blockIdx.x & 7, nch = blockIdx.x >> 3;
  const int n = (nch << 7) + (t & 127);
  const int chalf = t >> 7, c0 = chalf << 5;

  const float* xb = x + (((size_t)(b * 64 + c0)) << 12) + n;
  unsigned short* fb = fbf + (((size_t)(b * 64 + c0)) << 12) + n;
  float sq = 0.f;
  unsigned int pk[16];
#pragma unroll
  for (int cc = 0; cc < 16; ++cc) {
    float v0 = xb[(size_t)(2 * cc) << 12];
    float v1 = xb[(size_t)(2 * cc + 1) << 12];
    sq = __builtin_fmaf(v0, v0, sq);
    sq = __builtin_fmaf(v1, v1, sq);
    unsigned short w0 = f2bf_rne(v0), w1 = f2bf_rne(v1);
    pk[cc] = (unsigned int)w0 | ((unsigned int)w1 << 16);
    fb[(size_t)(2 * cc) << 12] = w0;
    fb[(size_t)(2 * cc + 1) << 12] = w1;
  }
  unsigned short* ft = fbf_t + ((size_t)b << 18) + (size_t)n * 64 + c0;
#pragma unroll
  for (int k = 0; k < 4; ++k) {
    uint4 u = make_uint4(pk[4 * k], pk[4 * k + 1], pk[4 * k + 2], pk[4 * k + 3]);
    *(uint4*)(ft + k * 8) = u;
  }
  if (chalf == 0) red[t] = sq;
  __syncthreads();
  if (chalf == 1) {
    float tot = sq + red[t & 127];
    g[b * 4096 + n] = tot;
    float m = tot;
    m = fmaxf(m, __shfl_xor(m, 1, 64));
    m = fmaxf(m, __shfl_xor(m, 2, 64));
    m = fmaxf(m, __shfl_xor(m, 4, 64));
    m = fmaxf(m, __shfl_xor(m, 8, 64));
    m = fmaxf(m, __shfl_xor(m, 16, 64));
    m = fmaxf(m, __shfl_xor(m, 32, 64));
    if ((t & 63) == 0) wmax[(t >> 6) & 1] = m;
  }
  __syncthreads();
  if (t == 0) bmax[b * 32 + nch] = fmaxf(wmax[0], wmax[1]);
}

// ============ main: S^T/O^T operand-swap flash attention, 16 waves/block ============
// 1024 threads = 4 qg (32 q-rows) x 4 kg (32 keys) -> 4 waves/SIMD for TLP.
// Double-buffered LDS, 1 barrier/iter, depth-2 global prefetch.
__global__ __launch_bounds__(1024) void chanattn_main(
    const float* __restrict__ x, const unsigned short* __restrict__ fbf_t,
    const unsigned short* __restrict__ fbf, const float* __restrict__ g,
    const float* __restrict__ bmax, float* __restrict__ out) {
  // buf p (+p*17920 u16): sKt u16[128][72] ; sVc u16[64][136] @+9216 u16
  // lred f32[128][4] @71680 B ; epilogue overlay Obuf f32[64][132] @0
  __shared__ __align__(16) unsigned char smem[73728];
  unsigned short* sKtB = (unsigned short*)smem;
  unsigned short* sVcB = (unsigned short*)(smem + 18432);
  float* lred = (float*)(smem + 71680);
  const int BUF = 17920;

  const int tid = threadIdx.x;
  const int wave = tid >> 6, lane = tid & 63, quad = lane >> 4, l15 = lane & 15;
  const int qg = wave >> 2, kg = wave & 3;
  const int b = blockIdx.x & 7, qt = blockIdx.x >> 3;

  const unsigned short* fT = fbf_t + ((size_t)b << 18);  // [n][c]
  const unsigned short* fV = fbf + ((size_t)b << 18);    // [c][n]

  const int sKey = tid >> 3, sC = (tid & 7) << 3;  // 1024 thr -> 1 b128 sKt each
  const int vC = tid >> 4, vK = (tid & 15) << 3;   // 1 v8s sVc each (2 b64 permuted)
  const int vSlot = (vK & ~31) + ((vK & 8) ? 16 : 0) + ((vK & 16) ? 4 : 0);

  // batch gmax from 32 per-chunk partials
  float gm = bmax[b * 32 + (lane & 31)];
  gm = fmaxf(gm, __shfl_xor(gm, 1, 64));
  gm = fmaxf(gm, __shfl_xor(gm, 2, 64));
  gm = fmaxf(gm, __shfl_xor(gm, 4, 64));
  gm = fmaxf(gm, __shfl_xor(gm, 8, 64));
  gm = fmaxf(gm, __shfl_xor(gm, 16, 64));
  float gq[2];
#pragma unroll
  for (int jq = 0; jq < 2; ++jq)
    gq[jq] = g[b * 4096 + qt * 128 + qg * 32 + jq * 16 + l15];

  // ---- stage Q tile into buf0 sKt ----
  *(v8s*)&sKtB[sKey * 72 + sC] =
      *(const v8s*)&fT[(size_t)(qt * 128 + sKey) * 64 + sC];
  // issue tile-0 loads
  v8s pfk = *(const v8s*)&fT[(size_t)sKey * 64 + sC];
  v8s pfv = *(const v8s*)&fV[(size_t)vC * 4096 + vK];

  __syncthreads();
  v8s bQ[2][2];   // Q B-frags (32 q-rows per qg), static all kernel
#pragma unroll
  for (int jq = 0; jq < 2; ++jq)
#pragma unroll
    for (int cs = 0; cs < 2; ++cs)
      bQ[jq][cs] = *(const v8s*)&sKtB[(qg * 32 + jq * 16 + l15) * 72 + cs * 32 + quad * 8];
  float msc[2];
#pragma unroll
  for (int jq = 0; jq < 2; ++jq) msc[jq] = __builtin_sqrtf(gq[jq] * gm) * LOG2E;
  __syncthreads();   // bQ reads done -> buf0 reusable

  // write tile 0 -> buf0; issue tile-1 loads
  *(v8s*)&sKtB[sKey * 72 + sC] = pfk;
  {
    v4s lo, hi;
#pragma unroll
    for (int j = 0; j < 4; ++j) { lo[j] = pfv[j]; hi[j] = pfv[j + 4]; }
    *(v4s*)&sVcB[vC * 136 + vSlot] = lo;
    *(v4s*)&sVcB[vC * 136 + vSlot + 8] = hi;
  }
  pfk = *(const v8s*)&fT[(size_t)(128 + sKey) * 64 + sC];
  pfv = *(const v8s*)&fV[(size_t)vC * 4096 + 128 + vK];

  v4f oacc[4][2];
  float rsum[2];
#pragma unroll
  for (int ct = 0; ct < 4; ++ct)
#pragma unroll
    for (int jq = 0; jq < 2; ++jq) oacc[ct][jq] = (v4f){0.f, 0.f, 0.f, 0.f};
  rsum[0] = 0.f; rsum[1] = 0.f;

  for (int kt = 0; kt < 32; ++kt) {
    __syncthreads();   // tile kt visible; prior reads of other buf done
    const int po = (kt & 1) * BUF;
    const int pn = ((kt & 1) ^ 1) * BUF;

    // LDS frag reads for tile kt (kg's 32 keys)
    v8s aK[2][2];
#pragma unroll
    for (int t = 0; t < 2; ++t)
#pragma unroll
      for (int cs = 0; cs < 2; ++cs)
        aK[t][cs] =
            *(const v8s*)&sKtB[po + (kg * 32 + t * 16 + l15) * 72 + cs * 32 + quad * 8];
    v8s aV[4];
#pragma unroll
    for (int ct = 0; ct < 4; ++ct)
      aV[ct] = *(const v8s*)&sVcB[po + (ct * 16 + l15) * 136 + kg * 32 + quad * 8];

    // ---- compute jq=0 first (MFMA in flight before staging/vm waits) ----
    {
      const int jq = 0;
      v4f s0 = (v4f){0.f, 0.f, 0.f, 0.f}, s1 = (v4f){0.f, 0.f, 0.f, 0.f};
#pragma unroll
      for (int cs = 0; cs < 2; ++cs) {
        s0 = __builtin_amdgcn_mfma_f32_16x16x32_bf16(aK[0][cs], bQ[jq][cs], s0, 0, 0, 0);
        s1 = __builtin_amdgcn_mfma_f32_16x16x32_bf16(aK[1][cs], bQ[jq][cs], s1, 0, 0, 0);
      }
      float p0[4], p1[4];
#pragma unroll
      for (int r = 0; r < 4; ++r) {
        p0[r] = __builtin_amdgcn_exp2f(__builtin_fmaf(s0[r], LOG2E, -msc[jq]));
        p1[r] = __builtin_amdgcn_exp2f(__builtin_fmaf(s1[r], LOG2E, -msc[jq]));
      }
      rsum[jq] += ((p0[0] + p0[1]) + (p0[2] + p0[3])) +
                  ((p1[0] + p1[1]) + (p1[2] + p1[3]));
      uint4 up;
      up.x = pack_hi16(p0[1], p0[0]);
      up.y = pack_hi16(p0[3], p0[2]);
      up.z = pack_hi16(p1[1], p1[0]);
      up.w = pack_hi16(p1[3], p1[2]);
      v8s bp = __builtin_bit_cast(v8s, up);
#pragma unroll
      for (int ct = 0; ct < 4; ++ct)
        oacc[ct][jq] =
            __builtin_amdgcn_mfma_f32_16x16x32_bf16(aV[ct], bp, oacc[ct][jq], 0, 0, 0);
    }

    // ---- staging writes for tile kt+1, then issue tile kt+2 loads ----
    if (kt < 31) {
      *(v8s*)&sKtB[pn + sKey * 72 + sC] = pfk;
      v4s lo, hi;
#pragma unroll
      for (int j = 0; j < 4; ++j) { lo[j] = pfv[j]; hi[j] = pfv[j + 4]; }
      *(v4s*)&sVcB[pn + vC * 136 + vSlot] = lo;
      *(v4s*)&sVcB[pn + vC * 136 + vSlot + 8] = hi;
    }
    if (kt < 30) {
      const int k0 = (kt + 2) << 7;
      pfk = *(const v8s*)&fT[(size_t)(k0 + sKey) * 64 + sC];
      pfv = *(const v8s*)&fV[(size_t)vC * 4096 + k0 + vK];
    }

    // ---- jq=1 ----
    {
      const int jq = 1;
      v4f s0 = (v4f){0.f, 0.f, 0.f, 0.f}, s1 = (v4f){0.f, 0.f, 0.f, 0.f};
#pragma unroll
      for (int cs = 0; cs < 2; ++cs) {
        s0 = __builtin_amdgcn_mfma_f32_16x16x32_bf16(aK[0][cs], bQ[jq][cs], s0, 0, 0, 0);
        s1 = __builtin_amdgcn_mfma_f32_16x16x32_bf16(aK[1][cs], bQ[jq][cs], s1, 0, 0, 0);
      }
      float p0[4], p1[4];
#pragma unroll
      for (int r = 0; r < 4; ++r) {
        p0[r] = __builtin_amdgcn_exp2f(__builtin_fmaf(s0[r], LOG2E, -msc[jq]));
        p1[r] = __builtin_amdgcn_exp2f(__builtin_fmaf(s1[r], LOG2E, -msc[jq]));
      }
      rsum[jq] += ((p0[0] + p0[1]) + (p0[2] + p0[3])) +
                  ((p1[0] + p1[1]) + (p1[2] + p1[3]));
      uint4 up;
      up.x = pack_hi16(p0[1], p0[0]);
      up.y = pack_hi16(p0[3], p0[2]);
      up.z = pack_hi16(p1[1], p1[0]);
      up.w = pack_hi16(p1[3], p1[2]);
      v8s bp = __builtin_bit_cast(v8s, up);
#pragma unroll
      for (int ct = 0; ct < 4; ++ct)
        oacc[ct][jq] =
            __builtin_amdgcn_mfma_f32_16x16x32_bf16(aV[ct], bp, oacc[ct][jq], 0, 0, 0);
    }
  }

  // ---- epilogue: fold l over quads + kg waves, merge O^T partials, store ----
#pragma unroll
  for (int jq = 0; jq < 2; ++jq) {
    float s = rsum[jq];
    s += __shfl_xor(s, 16, 64);
    s += __shfl_xor(s, 32, 64);
    rsum[jq] = s;
  }
  if (quad == 0) {
#pragma unroll
    for (int jq = 0; jq < 2; ++jq)
      lred[(qg * 32 + jq * 16 + l15) * 4 + kg] = rsum[jq];
  }
  __syncthreads();
  float inv[2];
#pragma unroll
  for (int jq = 0; jq < 2; ++jq) {
    const float4 lv = *(const float4*)&lred[(qg * 32 + jq * 16 + l15) * 4];
    inv[jq] = __builtin_amdgcn_rcpf((lv.x + lv.y) + (lv.z + lv.w));
  }

  float* Obuf = (float*)smem;   // [64 c][132 q]
#pragma unroll
  for (int round = 0; round < 4; ++round) {
    if (kg == round) {
#pragma unroll
      for (int ct = 0; ct < 4; ++ct)
#pragma unroll
        for (int jq = 0; jq < 2; ++jq)
#pragma unroll
          for (int r = 0; r < 4; ++r) {
            float val = oacc[ct][jq][r] * inv[jq];
            float* p = &Obuf[(ct * 16 + quad * 4 + r) * 132 + qg * 32 + jq * 16 + l15];
            if (round == 0) *p = val; else *p += val;
          }
    }
    __syncthreads();
  }
#pragma unroll
  for (int j = 0; j < 2; ++j) {
    int idx = tid + j * 1024;           // 0..2047 over (c, q4)
    int c = idx >> 5, q4 = idx & 31;
    const float4 o = *(const float4*)&Obuf[c * 132 + q4 * 4];
    size_t gidx = ((size_t)(b * 64 + c) << 12) + (unsigned)(qt * 128 + q4 * 4);
    const float4 xv = *(const float4*)(x + gidx);
    float4 rv;
    rv.x = xv.x + o.x; rv.y = xv.y + o.y; rv.z = xv.z + o.z; rv.w = xv.w + o.w;
    *(float4*)(out + gidx) = rv;
  }
}

// ============ fallback (R1 kernel, proven correct) if ws too small ============
__global__ __launch_bounds__(512) void
chanattn_fallback(const float* __restrict__ x, float* __restrict__ out) {
  __shared__ __align__(16) unsigned char smem[54272];
  unsigned short* sKt = (unsigned short*)smem;
  unsigned short* sVc = (unsigned short*)(smem + 18432);
  unsigned short* sP  = (unsigned short*)(smem + 35840);
  const int tid = threadIdx.x;
  const int wave = tid >> 6, lane = tid & 63, quad = lane >> 4, l15 = lane & 15;
  const int b = blockIdx.x & 7, qt = blockIdx.x >> 3;
  const float* fb = x + (size_t)b * (64 * 4096);
  const int skey = tid & 127, sc0 = (tid >> 7) << 4;
  {
    float vq[16];
#pragma unroll
    for (int j = 0; j < 16; ++j) vq[j] = fb[(sc0 + j) * 4096 + qt * 128 + skey];
    unsigned short us[16];
#pragma unroll
    for (int j = 0; j < 16; ++j) us[j] = f2bf_rne(vq[j]);
#pragma unroll
    for (int h = 0; h < 2; ++h) {
      v8s t;
#pragma unroll
      for (int j = 0; j < 8; ++j) t[j] = (short)us[h * 8 + j];
      *(v8s*)&sKt[skey * 72 + sc0 + h * 8] = t;
    }
  }
  float vk[16];
#pragma unroll
  for (int j = 0; j < 16; ++j) vk[j] = fb[(sc0 + j) * 4096 + skey];
  __syncthreads();
  v8s aq[2];
#pragma unroll
  for (int cs = 0; cs < 2; ++cs)
    aq[cs] = *(const v8s*)&sKt[(wave * 16 + l15) * 72 + cs * 32 + quad * 8];
  __syncthreads();
  v4f oacc[4];
#pragma unroll
  for (int ct = 0; ct < 4; ++ct) oacc[ct] = (v4f){0.f, 0.f, 0.f, 0.f};
  float m_run[4], l_run[4];
#pragma unroll
  for (int r = 0; r < 4; ++r) { m_run[r] = -3.0e38f; l_run[r] = 0.f; }
  unsigned short* sPw = sP + wave * (16 * 72);
  for (int kt = 0; kt < 32; ++kt) {
    {
      unsigned short us[16];
#pragma unroll
      for (int j = 0; j < 16; ++j) us[j] = f2bf_rne(vk[j]);
#pragma unroll
      for (int h = 0; h < 2; ++h) {
        v8s t;
#pragma unroll
        for (int j = 0; j < 8; ++j) t[j] = (short)us[h * 8 + j];
        *(v8s*)&sKt[skey * 72 + sc0 + h * 8] = t;
      }
#pragma unroll
      for (int j = 0; j < 16; ++j) sVc[(sc0 + j) * 136 + skey] = us[j];
    }
    __syncthreads();
    if (kt + 1 < 32) {
      const int m0 = (kt + 1) * 128;
#pragma unroll
      for (int j = 0; j < 16; ++j) vk[j] = fb[(sc0 + j) * 4096 + m0 + skey];
    }
    v4f sacc[8];
#pragma unroll
    for (int t = 0; t < 8; ++t) {
      v4f acc = (v4f){0.f, 0.f, 0.f, 0.f};
#pragma unroll
      for (int cs = 0; cs < 2; ++cs) {
        v8s bf = *(const v8s*)&sKt[(t * 16 + l15) * 72 + cs * 32 + quad * 8];
        acc = __builtin_amdgcn_mfma_f32_16x16x32_bf16(aq[cs], bf, acc, 0, 0, 0);
      }
      sacc[t] = acc;
    }
    float alpha[4], msc[4], rsum[4];
#pragma unroll
    for (int r = 0; r < 4; ++r) {
      float mv = sacc[0][r];
#pragma unroll
      for (int t = 1; t < 8; ++t) mv = fmaxf(mv, sacc[t][r]);
      mv = fmaxf(mv, __shfl_xor(mv, 8, 64));
      mv = fmaxf(mv, __shfl_xor(mv, 4, 64));
      mv = fmaxf(mv, __shfl_xor(mv, 2, 64));
      mv = fmaxf(mv, __shfl_xor(mv, 1, 64));
      float mnew = fmaxf(m_run[r], mv);
      alpha[r] = __builtin_amdgcn_exp2f((m_run[r] - mnew) * LOG2E);
      m_run[r] = mnew;
      msc[r] = mnew * LOG2E;
      l_run[r] *= alpha[r];
      rsum[r] = 0.f;
    }
#pragma unroll
    for (int ct = 0; ct < 4; ++ct)
#pragma unroll
      for (int r = 0; r < 4; ++r) oacc[ct][r] *= alpha[r];
#pragma unroll
    for (int half = 0; half < 2; ++half) {
#pragma unroll
      for (int t = half * 4; t < half * 4 + 4; ++t)
#pragma unroll
        for (int r = 0; r < 4; ++r) {
          float p = __builtin_amdgcn_exp2f(__builtin_fmaf(sacc[t][r], LOG2E, -msc[r]));
          rsum[r] += p;
          sPw[(quad * 4 + r) * 72 + (t - half * 4) * 16 + l15] = f2bf_rne(p);
        }
      asm volatile("s_waitcnt lgkmcnt(0)" ::: "memory");
#pragma unroll
      for (int ms = 0; ms < 2; ++ms) {
        v8s af = *(const v8s*)&sPw[l15 * 72 + ms * 32 + quad * 8];
#pragma unroll
        for (int ct = 0; ct < 4; ++ct) {
          v8s bf = *(const v8s*)&sVc[(ct * 16 + l15) * 136 + (half * 2 + ms) * 32 + quad * 8];
          oacc[ct] = __builtin_amdgcn_mfma_f32_16x16x32_bf16(af, bf, oacc[ct], 0, 0, 0);
        }
      }
      asm volatile("s_waitcnt lgkmcnt(0)" ::: "memory");
    }
#pragma unroll
    for (int r = 0; r < 4; ++r) {
      float s = rsum[r];
      s += __shfl_xor(s, 8, 64);
      s += __shfl_xor(s, 4, 64);
      s += __shfl_xor(s, 2, 64);
      s += __shfl_xor(s, 1, 64);
      l_run[r] += s;
    }
    __syncthreads();
  }
  float inv[4];
#pragma unroll
  for (int r = 0; r < 4; ++r) inv[r] = __builtin_amdgcn_rcpf(l_run[r]);
  float* sOt = (float*)smem;
#pragma unroll
  for (int ct = 0; ct < 4; ++ct)
#pragma unroll
    for (int r = 0; r < 4; ++r)
      sOt[(ct * 16 + l15) * 132 + wave * 16 + quad * 4 + r] = oacc[ct][r] * inv[r];
  __syncthreads();
#pragma unroll
  for (int j = 0; j < 4; ++j) {
    int idx = tid + j * 512;
    int nv = idx & 31, c = idx >> 5;
    float4 o = *(const float4*)&sOt[c * 132 + nv * 4];
    size_t gaddr = (size_t)b * (64 * 4096) + (size_t)c * 4096 + (size_t)(qt * 128 + nv * 4);
    float4 xv = *(const float4*)(x + gaddr);
    float4 res = make_float4(xv.x + o.x, xv.y + o.y, xv.z + o.z, xv.w + o.w);
    *(float4*)(out + gaddr) = res;
  }
}

extern "C" void kernel_launch(void* const* d_in, const int* in_sizes, int n_in,
                              void* d_out, int out_size, void* d_ws, size_t ws_size,
                              hipStream_t stream) {
  const float* xin = (const float*)d_in[0];
  float* out = (float*)d_out;
  if (ws_size >= (size_t)WS_NEED) {
    unsigned short* fbf_t = (unsigned short*)((char*)d_ws + WS_FBF_T);
    unsigned short* fbf = (unsigned short*)((char*)d_ws + WS_FBF);
    float* g = (float*)((char*)d_ws + WS_G);
    float* bmax = (float*)((char*)d_ws + WS_BMAX);
    prep_kernel<<<dim3(256), dim3(256), 0, stream>>>(xin, fbf_t, fbf, g, bmax);
    chanattn_main<<<dim3(256), dim3(1024), 0, stream>>>(xin, fbf_t, fbf, g, bmax, out);
  } else {
    chanattn_fallback<<<dim3(256), dim3(512), 0, stream>>>(xin, out);
  }
}